// Round 9
// baseline (600.722 us; speedup 1.0000x reference)
//
#include <hip/hip_runtime.h>
#include <hip/hip_bf16.h>

#define TT 2048
#define BB 16
#define DD 1024
#define BD (BB*DD)          // 16384 cols per time row
#define MR (TT*BB)          // 32768 GEMM rows
#define EPSV 1e-6f
#define INVD (1.0f/1024.0f)
#define CH 256              // phase-B chunk length
#define NCH (TT/CH)         // 8
#define RING 8              // phase-A register ring depth (bf16 rows)

typedef __bf16 bf16x8_t __attribute__((ext_vector_type(8)));
typedef float  f32x4_t  __attribute__((ext_vector_type(4)));
typedef float  f32x2    __attribute__((ext_vector_type(2)));
typedef unsigned int u32x4 __attribute__((ext_vector_type(4)));
typedef __attribute__((address_space(1))) void gvoid_t;
typedef __attribute__((address_space(3))) void lvoid_t;
typedef __attribute__((address_space(3))) float2 lds_f2;

union F4 { f32x4_t q; float4 v; f32x2 h[2]; float f[4]; };

static __device__ __forceinline__ f32x2 pk_mul(f32x2 a, f32x2 b) {
    f32x2 d; asm("v_pk_mul_f32 %0, %1, %2" : "=v"(d) : "v"(a), "v"(b)); return d;
}
static __device__ __forceinline__ f32x2 pk_fma(f32x2 a, f32x2 b, f32x2 c) {
    f32x2 d; asm("v_pk_fma_f32 %0, %1, %2, %3" : "=v"(d) : "v"(a), "v"(b), "v"(c)); return d;
}
static __device__ __forceinline__ f32x2 pk_add(f32x2 a, f32x2 b) {
    f32x2 d; asm("v_pk_add_f32 %0, %1, %2" : "=v"(d) : "v"(a), "v"(b)); return d;
}
// wave64 DPP sum -> total in lane 63 -> broadcast via readlane (HW-verified v2-v8)
static __device__ __forceinline__ float wave_red_sum(float ss) {
    asm volatile(
        "s_nop 1\n\t"
        "v_add_f32 %0, %0, %0 row_shr:1 bound_ctrl:0\n\t"
        "s_nop 1\n\t"
        "v_add_f32 %0, %0, %0 row_shr:2 bound_ctrl:0\n\t"
        "s_nop 1\n\t"
        "v_add_f32 %0, %0, %0 row_shr:4 bank_mask:0xe\n\t"
        "s_nop 1\n\t"
        "v_add_f32 %0, %0, %0 row_shr:8 bank_mask:0xc\n\t"
        "s_nop 1\n\t"
        "v_add_f32 %0, %0, %0 row_bcast:15 row_mask:0xa\n\t"
        "s_nop 1\n\t"
        "v_add_f32 %0, %0, %0 row_bcast:31 row_mask:0xc\n\t"
        "s_nop 1"
        : "+v"(ss));
    return __builtin_bit_cast(float, __builtin_amdgcn_readlane(__builtin_bit_cast(int, ss), 63));
}

static __device__ __forceinline__ unsigned short f2bf(float f) {
    __hip_bfloat16 h = __float2bfloat16(f);
    return __builtin_bit_cast(unsigned short, h);
}

// unpack 16 bf16 (two dwordx4) -> 8 f32x2 pairs; elem (2i,2i+1) = (lo,hi) of u32 i
static __device__ __forceinline__ void unpack_row(const u32x4* r, f32x2* w) {
    #pragma unroll
    for (int i = 0; i < 4; ++i) {
        w[i][0]     = __builtin_bit_cast(float, r[0][i] << 16);
        w[i][1]     = __builtin_bit_cast(float, r[0][i] & 0xFFFF0000u);
        w[4 + i][0] = __builtin_bit_cast(float, r[1][i] << 16);
        w[4 + i][1] = __builtin_bit_cast(float, r[1][i] & 0xFFFF0000u);
    }
}

// ---------------------------------------------------------------------------
// K0: convert x and W to bf16 (unchanged, proven)
// ---------------------------------------------------------------------------
__global__ void k_convert(const float* __restrict__ x, const float* __restrict__ W,
                          unsigned short* __restrict__ xb, unsigned short* __restrict__ wb) {
    const long NX4 = (long)MR * DD / 4;
    const long NW4 = (long)DD * DD / 4;
    const long stride = (long)gridDim.x * blockDim.x;
    for (long j = (long)blockIdx.x * blockDim.x + threadIdx.x; j < NX4 + NW4; j += stride) {
        const float4* src; unsigned short* dst; long o;
        if (j < NX4) { src = (const float4*)x; dst = xb; o = j; }
        else         { src = (const float4*)W; dst = wb; o = j - NX4; }
        float4 v = src[o];
        ushort4 u;
        u.x = f2bf(v.x); u.y = f2bf(v.y); u.z = f2bf(v.z); u.w = f2bf(v.w);
        *(ushort4*)(dst + o * 4) = u;
    }
}

// ---------------------------------------------------------------------------
// K1: Wx = x @ W^T + b  (bf16 MFMA). Unchanged, proven.
// ---------------------------------------------------------------------------
__global__ __launch_bounds__(256, 2)
void k_gemm(const unsigned short* __restrict__ A, const unsigned short* __restrict__ Bw,
            const float* __restrict__ bias, float* __restrict__ C) {
    __shared__ char lds[16384];
    char* ldsA = lds;
    char* ldsB = lds + 8192;
    const int tid  = threadIdx.x;
    const int lane = tid & 63;
    const int wid  = tid >> 6;
    const int wm = wid >> 1, wn = wid & 1;
    const size_t arow0 = (size_t)blockIdx.y * 128;
    const int    brow0 = blockIdx.x * 128;

    f32x4_t acc[4][4] = {};

    const int off0 = tid * 16,        row0_ = off0 >> 6, colb0 = off0 & 63;
    const int off1 = 4096 + tid * 16, row1_ = off1 >> 6, colb1 = off1 & 63;

    for (int kk = 0; kk < DD / 32; ++kk) {
        const int kbase = kk * 32;
        __builtin_amdgcn_global_load_lds(
            (gvoid_t*)(A + (arow0 + row0_) * DD + kbase + (colb0 >> 1)),
            (lvoid_t*)(ldsA + off0), 16, 0, 0);
        __builtin_amdgcn_global_load_lds(
            (gvoid_t*)(A + (arow0 + row1_) * DD + kbase + (colb1 >> 1)),
            (lvoid_t*)(ldsA + off1), 16, 0, 0);
        __builtin_amdgcn_global_load_lds(
            (gvoid_t*)(Bw + (size_t)(brow0 + row0_) * DD + kbase + (colb0 >> 1)),
            (lvoid_t*)(ldsB + off0), 16, 0, 0);
        __builtin_amdgcn_global_load_lds(
            (gvoid_t*)(Bw + (size_t)(brow0 + row1_) * DD + kbase + (colb1 >> 1)),
            (lvoid_t*)(ldsB + off1), 16, 0, 0);
        __syncthreads();

        const int ml = lane & 15;
        const int kh = (lane >> 4) * 16;
        bf16x8_t av[4], bv[4];
        #pragma unroll
        for (int i = 0; i < 4; ++i) {
            av[i] = *(const bf16x8_t*)(ldsA + (wm * 64 + i * 16 + ml) * 64 + kh);
            bv[i] = *(const bf16x8_t*)(ldsB + (wn * 64 + i * 16 + ml) * 64 + kh);
        }
        #pragma unroll
        for (int i = 0; i < 4; ++i)
            #pragma unroll
            for (int j = 0; j < 4; ++j)
                acc[i][j] = __builtin_amdgcn_mfma_f32_16x16x32_bf16(av[i], bv[j], acc[i][j], 0, 0, 0);
        __syncthreads();
    }

    const int rq = (lane >> 4) * 4;
    const int cl = lane & 15;
    #pragma unroll
    for (int i = 0; i < 4; ++i) {
        #pragma unroll
        for (int j = 0; j < 4; ++j) {
            const int n = brow0 + wn * 64 + j * 16 + cl;
            const float bb = bias[n];
            #pragma unroll
            for (int q = 0; q < 4; ++q) {
                const size_t m = arow0 + wm * 64 + i * 16 + rq + q;
                C[m * DD + n] = acc[i][j][q] + bb;
            }
        }
    }
}

// ---------------------------------------------------------------------------
// K_GQ: data-only tables (proven) + NEW: bf16 copy of Wx, laid out [b][t][d],
// for phase A's half-bandwidth stream. Each wave owns rows j0..j0+3 (= R[1..4]).
// ---------------------------------------------------------------------------
__global__ __launch_bounds__(256)
void k_gq(const float* __restrict__ Wx, const float* __restrict__ la,
          float2* __restrict__ gq_g, unsigned short* __restrict__ wxb) {
    const int b = blockIdx.y;
    const int wid = threadIdx.x >> 6, lane = threadIdx.x & 63;
    const int j0 = blockIdx.x * 16 + wid * 4;
    const float alpha = expf(la[0]);
    const float a2 = alpha * alpha;
    const int dof = lane * 4;
    const float* base = Wx + b * DD + dof;

    F4 R[5][4];
    #pragma unroll
    for (int jj = 0; jj < 5; ++jj) {
        const int row = max(j0 - 1 + jj, 0);
        #pragma unroll
        for (int k = 0; k < 4; ++k)
            R[jj][k].v = *(const float4*)(base + (size_t)row * BD + k * 256);
    }
    // bf16 copy of rows j0..j0+3
    {
        unsigned short* wdst = wxb + ((size_t)b * TT + j0) * DD + dof;
        #pragma unroll
        for (int sI = 0; sI < 4; ++sI) {
            #pragma unroll
            for (int k = 0; k < 4; ++k) {
                float4 v = R[sI + 1][k].v;
                ushort4 u;
                u.x = f2bf(v.x); u.y = f2bf(v.y); u.z = f2bf(v.z); u.w = f2bf(v.w);
                *(ushort4*)(wdst + (size_t)sI * DD + k * 256) = u;
            }
        }
    }
    float red[8];
    #pragma unroll
    for (int sI = 0; sI < 4; ++sI) {
        float g = 0.f, q = 0.f;
        #pragma unroll
        for (int k = 0; k < 4; ++k)
            #pragma unroll
            for (int j = 0; j < 4; ++j) {
                const float w0 = R[sI][k].f[j], w1 = R[sI + 1][k].f[j];
                g = fmaf(w0, w1, g);
                q = fmaf(w1, w1, q);
            }
        red[sI] = g; red[4 + sI] = q;
    }
    #pragma unroll
    for (int m = 1; m < 64; m <<= 1)
        #pragma unroll
        for (int k = 0; k < 8; ++k)
            red[k] += __shfl_xor(red[k], m, 64);
    if (lane == 0) {
        #pragma unroll
        for (int sI = 0; sI < 4; ++sI) {
            const int j = j0 + sI;
            gq_g[(size_t)b * TT + j] =
                make_float2(j == 0 ? 0.f : a2 * red[sI], a2 * red[4 + sI]);
        }
    }
}

// ---------------------------------------------------------------------------
// K2: phase A v9 — v7's proven single-wave register ring, but streaming bf16
// Wx (HALF the bytes; v3/v6/v7/v8 all pinned at ~26 GB/s per-CU HBM cap).
// 2x global_load_dwordx4 per step; in-register bf16 unpack (shift/mask);
// q = hraw/alpha substitution (q_t = r*q + w, saves 8 pk_mul); ss-recurrence
// scalar chain (validated v4-v8). Snapshots h_512/1024/1536 go to spare rows
// 257..259 (phase-B pass 0 reads them; no aliasing with the bf16 Wx region).
// ---------------------------------------------------------------------------
__global__ __launch_bounds__(64, 1)
void k_phaseA(const unsigned short* __restrict__ Wxb, const float* __restrict__ h0,
              const float* __restrict__ la, const float2* __restrict__ gq_g,
              float* __restrict__ hreg, float* __restrict__ rtab) {
    __shared__ float2 gqlds[TT];   // 16 KB
    const int b = blockIdx.x;
    const int lane = threadIdx.x;
    const int eoff = lane * 16;    // this lane's 16 consecutive elements
    const float alpha = expf(la[0]);
    const float a2 = alpha * alpha;
    const unsigned short* wbase = Wxb + (size_t)b * TT * DD + eoff;

    // gq preload: 1024 float4 = 16 per lane
    {
        const float4* src = (const float4*)(gq_g + (size_t)b * TT);
        float4* dst = (float4*)gqlds;
        #pragma unroll
        for (int i = 0; i < 16; ++i) dst[i * 64 + lane] = src[i * 64 + lane];
    }
    // h0 -> q0 = h0/alpha; emit h output row 0
    f32x2 q[8];
    {
        const float inva = 1.0f / alpha;
        #pragma unroll
        for (int k = 0; k < 4; ++k) {
            float4 v = *(const float4*)(h0 + b * DD + eoff + k * 4);
            *(float4*)(hreg + b * DD + eoff + k * 4) = v;
            q[2*k][0]   = v.x * inva; q[2*k][1]   = v.y * inva;
            q[2*k+1][0] = v.z * inva; q[2*k+1][1] = v.w * inva;
        }
    }
    asm volatile("" :: "v"(q[0]), "v"(q[1]), "v"(q[2]), "v"(q[3]),
                       "v"(q[4]), "v"(q[5]), "v"(q[6]), "v"(q[7]));
    asm volatile("s_waitcnt lgkmcnt(0)" ::: "memory");   // gqlds writes done
    __builtin_amdgcn_sched_barrier(0);

    // issue bf16 register ring: rows 0..7 (= w_1..w_8), 2 dwordx4 each
    u32x4 ring[RING][2];
    #pragma unroll
    for (int s = 0; s < RING; ++s) {
        const unsigned short* wp = wbase + (size_t)s * DD;
        asm volatile("global_load_dwordx4 %0, %1, off" : "=v"(ring[s][0]) : "v"(wp));
        asm volatile("global_load_dwordx4 %0, %1, off" : "=v"(ring[s][1]) : "v"(wp + 8));
    }
    asm volatile("s_waitcnt vmcnt(12)" ::: "memory");    // rows 0,1 landed
    __builtin_amdgcn_sched_barrier(0);

    f32x2 wf[4][8];                 // unpacked rows, indexed by row&3 (static)
    unpack_row(ring[0], wf[0]);
    unpack_row(ring[1], wf[1]);

    // prologue: ss0 = |h0|^2 = a2*|q0|^2; e-seeds (v7 semantics, a2-scaled)
    float ss, ee[2], vr1 = 1.f, vr2 = 1.f;
    {
        f32x2 sa = pk_mul(q[0], q[0]);
        #pragma unroll
        for (int p = 1; p < 8; ++p) sa = pk_fma(q[p], q[p], sa);
        ss = a2 * wave_red_sum(sa[0] + sa[1]);
        f32x2 da = pk_mul(q[0], wf[0][0]);
        f32x2 ea = pk_mul(q[0], wf[1][0]);
        #pragma unroll
        for (int p = 1; p < 8; ++p) {
            da = pk_fma(q[p], wf[0][p], da);
            ea = pk_fma(q[p], wf[1][p], ea);
        }
        ee[1] = a2 * wave_red_sum(da[0] + da[1]);   // e for t=1 (pe=1)
        ee[0] = a2 * wave_red_sum(ea[0] + ea[1]);   // e for t=2 (pe=0)
    }
    f32x2 g2v[2];
    asm volatile("ds_read_b64 %0, %1" : "=v"(g2v[1]) : "v"((lds_f2*)&gqlds[0]));
    asm volatile("ds_read_b64 %0, %1" : "=v"(g2v[0]) : "v"((lds_f2*)&gqlds[1]));
    asm volatile("s_waitcnt lgkmcnt(0)" ::: "memory");
    __builtin_amdgcn_sched_barrier(0);

    float r_keep = 0.f;

    for (int tt = 0; tt < TT; tt += RING) {
        #pragma unroll
        for (int s = 0; s < RING; ++s) {
            const int m = tt + s;            // step index; t = m+1
            const int pe = (s + 1) & 1;      // t parity

            if (s == 0 && tt >= 512 && (tt & 511) == 0) {   // snapshot h_m -> row 256+m/512
                float* hp = hreg + (size_t)(256 + (tt >> 9)) * BD + b * DD + eoff;
                const float svr = vr1 * alpha;
                #pragma unroll
                for (int k = 0; k < 4; ++k) {
                    float4 v;
                    v.x = q[2*k][0] * svr;   v.y = q[2*k][1] * svr;
                    v.z = q[2*k+1][0] * svr; v.w = q[2*k+1][1] * svr;
                    *(float4*)(hp + k * 4) = v;
                }
            }

            // rows m..m+2 landed once <=10 loads outstanding (rows m+3..m+7)
            asm volatile("s_waitcnt vmcnt(10)" ::: "memory");
            __builtin_amdgcn_sched_barrier(0);
            unpack_row(ring[(s + 2) & (RING - 1)], wf[(s + 2) & 3]);   // row m+2

            // g2 read issued at step m-2 complete once <=1 ds op outstanding
            asm volatile("s_waitcnt lgkmcnt(1)" ::: "memory");
            __builtin_amdgcn_sched_barrier(0);

            // ---- scalar chain: ss_t = vr1*(vr1*ss + 2*(vr2*e_t + G_t)) + Q_t ----
            const float Dp = fmaf(vr2, ee[pe], g2v[pe][0]);
            const float u1 = fmaf(vr1, ss, Dp + Dp);
            ss = fmaf(vr1, u1, g2v[pe][1]);
            const float rt = __builtin_amdgcn_rsqf(fmaf(ss, INVD, EPSV));
            r_keep = (lane == (m & 63)) ? rt : r_keep;

            // ---- q_t = r_{t-1}*q_{t-1} + w_t   (row m = wf[s&3]) ----
            const f32x2 rr1 = {vr1, vr1};
            #pragma unroll
            for (int p = 0; p < 8; ++p)
                q[p] = pk_fma(rr1, q[p], wf[s & 3][p]);

            // ---- e_{t+2} = a2*dot(q_t, w_{t+2})  (row m+2 = wf[(s+2)&3]) ----
            {
                const f32x2* B = wf[(s + 2) & 3];
                f32x2 ea0 = pk_mul(q[0], B[0]);
                f32x2 ea1 = pk_mul(q[1], B[1]);
                f32x2 ea2 = pk_mul(q[2], B[2]);
                f32x2 ea3 = pk_mul(q[3], B[3]);
                ea0 = pk_fma(q[4], B[4], ea0);
                ea1 = pk_fma(q[5], B[5], ea1);
                ea2 = pk_fma(q[6], B[6], ea2);
                ea3 = pk_fma(q[7], B[7], ea3);
                ea0 = pk_add(ea0, ea1); ea2 = pk_add(ea2, ea3); ea0 = pk_add(ea0, ea2);
                ee[pe] = a2 * wave_red_sum(ea0[0] + ea0[1]);
            }

            // ---- prefetch {G,Q} for t+2 ----
            asm volatile("ds_read_b64 %0, %1"
                         : "=v"(g2v[pe]) : "v"((lds_f2*)&gqlds[(m + 2) & (TT - 1)]));

            // ---- refill slot s with row m+8 (wrap: dummy, never read) ----
            {
                const unsigned short* wp = wbase + (size_t)((m + RING) & (TT - 1)) * DD;
                asm volatile("global_load_dwordx4 %0, %1, off" : "=v"(ring[s][0]) : "v"(wp));
                asm volatile("global_load_dwordx4 %0, %1, off" : "=v"(ring[s][1]) : "v"(wp + 8));
            }

            vr2 = vr1; vr1 = rt;
        }

        if ((tt & 63) == 56)          // flush 64 r's (one per lane)
            rtab[(size_t)b * TT + (tt - 56) + lane] = r_keep;
    }

    asm volatile("s_waitcnt vmcnt(0) lgkmcnt(0)" ::: "memory");
}

// ---------------------------------------------------------------------------
// K3: phase B — parallel replay in TWO passes (even chunks, then odd chunks).
// Odd-chunk heads (rows 256,768,1280,1792) are written by pass 0 at final
// locations; even-chunk heads come from phase A (row 0) or snap rows 257..259.
// Writes ALL h rows unconditionally.
// ---------------------------------------------------------------------------
__global__ __launch_bounds__(256)
void k_phaseB(float* __restrict__ WxOut, float* __restrict__ hout,
              const float* __restrict__ rtab, const float* __restrict__ la, int pass) {
    const int col = blockIdx.x * 256 + threadIdx.x;
    const int c = blockIdx.y * 2 + pass;
    const int b = col >> 10;
    const float alpha = expf(la[0]);
    const float* rr = rtab + b * TT;
    const int headrow = (c == 0) ? 0 : ((c & 1) ? c * CH : 256 + (c >> 1));
    float h = hout[(size_t)headrow * BD + col];
    const int t0 = c * CH + 1;
    float w = WxOut[(size_t)(t0 - 1) * BD + col];
    for (int s = 0; s < CH; ++s) {
        const int t = t0 + s;
        float wnext = 0.f;
        if (s + 1 < CH) wnext = WxOut[(size_t)t * BD + col];
        const float r = rr[t - 1];
        const float hraw = fmaf(alpha, w, h);
        const float hn = r * hraw;
        const float sg = 1.0f / (1.0f + __expf(-hn));
        WxOut[(size_t)(t - 1) * BD + col] = hn * hn * sg;
        hout[(size_t)t * BD + col] = hn;
        h = hn;
        w = wnext;
    }
}

// ---------------------------------------------------------------------------
extern "C" void kernel_launch(void* const* d_in, const int* in_sizes, int n_in,
                              void* d_out, int out_size, void* d_ws, size_t ws_size,
                              hipStream_t stream) {
    (void)in_sizes; (void)n_in; (void)out_size; (void)ws_size;
    const float* x    = (const float*)d_in[0];
    const float* h0   = (const float*)d_in[1];
    const float* W    = (const float*)d_in[2];
    const float* bias = (const float*)d_in[3];
    const float* la   = (const float*)d_in[4];

    float* outr = (float*)d_out;                       // [T][B*D] : fp32 Wx -> out
    float* hreg = outr + (size_t)TT * BD;              // [T+1][B*D] : h output
    // hreg dead-space plan (rows of 64KB):
    //   xb  (bf16 x, 64MB)  rows 0..1023   : convert->gemm only
    //   wb  (bf16 W, 2MB)   rows 1024..1055: convert->gemm only
    //   gq_g (256KB)        rows 1..4      : k_gq -> phaseA (clobbers dead xb)
    //   wxb (bf16 Wx, 64MB) rows 1025..2048: k_gq -> phaseA (clobbers dead wb tail)
    //   snaps (3 rows)      rows 257..259  : phaseA -> phaseB pass 0
    // phaseB finally overwrites all h rows 1..2048 with real values.
    unsigned short* xb  = (unsigned short*)hreg;
    unsigned short* wb  = (unsigned short*)(hreg + (size_t)1024 * BD);
    float2*         gq_g = (float2*)(hreg + BD);
    unsigned short* wxb = (unsigned short*)(hreg + (size_t)1025 * BD);
    float*          rtab = (float*)d_ws;               // [B][T] = 128KB (proven size)

    k_convert<<<2048, 256, 0, stream>>>(x, W, xb, wb);
    k_gemm<<<dim3(DD / 128, MR / 128), 256, 0, stream>>>(xb, wb, bias, outr);
    k_gq<<<dim3(TT / 16, BB), 256, 0, stream>>>(outr, la, gq_g, wxb);
    k_phaseA<<<BB, 64, 0, stream>>>(wxb, h0, la, gq_g, hreg, rtab);
    k_phaseB<<<dim3(BD / 256, NCH / 2), 256, 0, stream>>>(outr, hreg, rtab, la, 0);
    k_phaseB<<<dim3(BD / 256, NCH / 2), 256, 0, stream>>>(outr, hreg, rtab, la, 1);
}

// Round 10
// 512.370 us; speedup vs baseline: 1.1724x; 1.1724x over previous
//
#include <hip/hip_runtime.h>
#include <hip/hip_bf16.h>

#define TT 2048
#define BB 16
#define DD 1024
#define BD (BB*DD)          // 16384 cols per time row
#define MR (TT*BB)          // 32768 GEMM rows
#define EPSV 1e-6f
#define INVD (1.0f/1024.0f)
#define CH 256              // phase-B chunk length
#define NCH (TT/CH)         // 8
#define RING 8              // phase-A register ring depth (rows)

typedef __bf16 bf16x8_t __attribute__((ext_vector_type(8)));
typedef float  f32x4_t  __attribute__((ext_vector_type(4)));
typedef __attribute__((address_space(1))) void gvoid_t;
typedef __attribute__((address_space(3))) void lvoid_t;

// wave64 DPP sum -> total in lane 63 -> broadcast via readlane (HW-verified v2-v9)
static __device__ __forceinline__ float wave_red_sum(float ss) {
    asm volatile(
        "s_nop 1\n\t"
        "v_add_f32 %0, %0, %0 row_shr:1 bound_ctrl:0\n\t"
        "s_nop 1\n\t"
        "v_add_f32 %0, %0, %0 row_shr:2 bound_ctrl:0\n\t"
        "s_nop 1\n\t"
        "v_add_f32 %0, %0, %0 row_shr:4 bank_mask:0xe\n\t"
        "s_nop 1\n\t"
        "v_add_f32 %0, %0, %0 row_shr:8 bank_mask:0xc\n\t"
        "s_nop 1\n\t"
        "v_add_f32 %0, %0, %0 row_bcast:15 row_mask:0xa\n\t"
        "s_nop 1\n\t"
        "v_add_f32 %0, %0, %0 row_bcast:31 row_mask:0xc\n\t"
        "s_nop 1"
        : "+v"(ss));
    return __builtin_bit_cast(float, __builtin_amdgcn_readlane(__builtin_bit_cast(int, ss), 63));
}

static __device__ __forceinline__ unsigned short f2bf(float f) {
    __hip_bfloat16 h = __float2bfloat16(f);
    return __builtin_bit_cast(unsigned short, h);
}

// ---------------------------------------------------------------------------
// K0: convert x and W to bf16 (r3-verbatim, proven)
// ---------------------------------------------------------------------------
__global__ void k_convert(const float* __restrict__ x, const float* __restrict__ W,
                          unsigned short* __restrict__ xb, unsigned short* __restrict__ wb) {
    const long NX4 = (long)MR * DD / 4;
    const long NW4 = (long)DD * DD / 4;
    const long stride = (long)gridDim.x * blockDim.x;
    for (long j = (long)blockIdx.x * blockDim.x + threadIdx.x; j < NX4 + NW4; j += stride) {
        const float4* src; unsigned short* dst; long o;
        if (j < NX4) { src = (const float4*)x; dst = xb; o = j; }
        else         { src = (const float4*)W; dst = wb; o = j - NX4; }
        float4 v = src[o];
        ushort4 u;
        u.x = f2bf(v.x); u.y = f2bf(v.y); u.z = f2bf(v.z); u.w = f2bf(v.w);
        *(ushort4*)(dst + o * 4) = u;
    }
}

// ---------------------------------------------------------------------------
// K1: Wx = x @ W^T + b  (bf16 MFMA). r3-verbatim, proven.
// ---------------------------------------------------------------------------
__global__ __launch_bounds__(256, 2)
void k_gemm(const unsigned short* __restrict__ A, const unsigned short* __restrict__ Bw,
            const float* __restrict__ bias, float* __restrict__ C) {
    __shared__ char lds[16384];
    char* ldsA = lds;
    char* ldsB = lds + 8192;
    const int tid  = threadIdx.x;
    const int lane = tid & 63;
    const int wid  = tid >> 6;
    const int wm = wid >> 1, wn = wid & 1;
    const size_t arow0 = (size_t)blockIdx.y * 128;
    const int    brow0 = blockIdx.x * 128;

    f32x4_t acc[4][4] = {};

    const int off0 = tid * 16,        row0_ = off0 >> 6, colb0 = off0 & 63;
    const int off1 = 4096 + tid * 16, row1_ = off1 >> 6, colb1 = off1 & 63;

    for (int kk = 0; kk < DD / 32; ++kk) {
        const int kbase = kk * 32;
        __builtin_amdgcn_global_load_lds(
            (gvoid_t*)(A + (arow0 + row0_) * DD + kbase + (colb0 >> 1)),
            (lvoid_t*)(ldsA + off0), 16, 0, 0);
        __builtin_amdgcn_global_load_lds(
            (gvoid_t*)(A + (arow0 + row1_) * DD + kbase + (colb1 >> 1)),
            (lvoid_t*)(ldsA + off1), 16, 0, 0);
        __builtin_amdgcn_global_load_lds(
            (gvoid_t*)(Bw + (size_t)(brow0 + row0_) * DD + kbase + (colb0 >> 1)),
            (lvoid_t*)(ldsB + off0), 16, 0, 0);
        __builtin_amdgcn_global_load_lds(
            (gvoid_t*)(Bw + (size_t)(brow0 + row1_) * DD + kbase + (colb1 >> 1)),
            (lvoid_t*)(ldsB + off1), 16, 0, 0);
        __syncthreads();

        const int ml = lane & 15;
        const int kh = (lane >> 4) * 16;
        bf16x8_t av[4], bv[4];
        #pragma unroll
        for (int i = 0; i < 4; ++i) {
            av[i] = *(const bf16x8_t*)(ldsA + (wm * 64 + i * 16 + ml) * 64 + kh);
            bv[i] = *(const bf16x8_t*)(ldsB + (wn * 64 + i * 16 + ml) * 64 + kh);
        }
        #pragma unroll
        for (int i = 0; i < 4; ++i)
            #pragma unroll
            for (int j = 0; j < 4; ++j)
                acc[i][j] = __builtin_amdgcn_mfma_f32_16x16x32_bf16(av[i], bv[j], acc[i][j], 0, 0, 0);
        __syncthreads();
    }

    const int rq = (lane >> 4) * 4;
    const int cl = lane & 15;
    #pragma unroll
    for (int i = 0; i < 4; ++i) {
        #pragma unroll
        for (int j = 0; j < 4; ++j) {
            const int n = brow0 + wn * 64 + j * 16 + cl;
            const float bb = bias[n];
            #pragma unroll
            for (int q = 0; q < 4; ++q) {
                const size_t m = arow0 + wm * 64 + i * 16 + rq + q;
                C[m * DD + n] = acc[i][j][q] + bb;
            }
        }
    }
}

// ---------------------------------------------------------------------------
// K2: phase A v10 — v3's proven register-ring + direct math, but the
// s_waitcnt executes once per 4-STEP GROUP instead of once per step
// (m135: a satisfied vmcnt wait still costs 156-332cy — the common
// ~200-250cy/step unexplained constant across v3/v6/v7/v8/v9).
// Group g covers rows m0..m0+3: one vmcnt(16) (rows m0+4..m0+7 in flight),
// 4 waitless steps from registers, then a 4-row refill. Lead = 2 groups.
// No LDS; r-table via lane-select register, flushed every 64 steps.
// ---------------------------------------------------------------------------
__global__ __launch_bounds__(64, 1)
void k_phaseA(const float* __restrict__ Wx, const float* __restrict__ h0,
              const float* __restrict__ la, float* __restrict__ hout,
              float* __restrict__ rtab) {
    const int b = blockIdx.x;
    const int lane = threadIdx.x;
    const int dof = lane * 4;
    const float alpha = expf(la[0]);
    const float* wbase = Wx + b * DD + dof;

    float h[16];
    #pragma unroll
    for (int k = 0; k < 4; ++k) {
        float4 v = *(const float4*)(h0 + b * DD + k * 256 + dof);
        h[k*4+0] = v.x; h[k*4+1] = v.y; h[k*4+2] = v.z; h[k*4+3] = v.w;
    }
    asm volatile("" :: "v"(h[0]), "v"(h[1]), "v"(h[2]), "v"(h[3]),
                       "v"(h[4]), "v"(h[5]), "v"(h[6]), "v"(h[7]),
                       "v"(h[8]), "v"(h[9]), "v"(h[10]), "v"(h[11]),
                       "v"(h[12]), "v"(h[13]), "v"(h[14]), "v"(h[15]));
    __builtin_amdgcn_sched_barrier(0);

    // prologue: issue rows 0..7 (32 loads)
    f32x4_t buf[RING][4];
    #pragma unroll
    for (int s = 0; s < RING; ++s) {
        const float* wp = wbase + (size_t)s * BD;
        #pragma unroll
        for (int k = 0; k < 4; ++k)
            asm volatile("global_load_dwordx4 %0, %1, off"
                         : "=v"(buf[s][k]) : "v"(wp + k * 256));
    }

    float r_keep = 0.f;

    for (int tt = 0; tt < TT; tt += 8) {
        #pragma unroll
        for (int g = 0; g < 2; ++g) {
            const int m0 = tt + g * 4;

            // ---- ONE wait per 4 steps: rows m0..m0+3 complete once the
            // 16 loads of rows m0+4..m0+7 are the only ones outstanding ----
            asm volatile("s_waitcnt vmcnt(16)" ::: "memory");
            __builtin_amdgcn_sched_barrier(0);

            if ((m0 & 255) == 0) {              // snapshot h_{m0} (chunk head)
                float* hp = hout + (size_t)m0 * BD + b * DD;
                #pragma unroll
                for (int k = 0; k < 4; ++k) {
                    float4 v; v.x = h[k*4+0]; v.y = h[k*4+1];
                    v.z = h[k*4+2]; v.w = h[k*4+3];
                    *(float4*)(hp + k * 256 + dof) = v;
                }
            }

            // ---- 4 waitless steps ----
            #pragma unroll
            for (int s4 = 0; s4 < 4; ++s4) {
                const int s = g * 4 + s4;       // ring slot (static)
                const int m = m0 + s4;          // step index; t = m+1
                float hr[16];
                float p0 = 0.f, p1 = 0.f, p2 = 0.f, p3 = 0.f;
                #pragma unroll
                for (int k = 0; k < 4; ++k) {
                    const f32x4_t w = buf[s][k];
                    hr[k*4+0] = fmaf(alpha, w[0], h[k*4+0]);
                    hr[k*4+1] = fmaf(alpha, w[1], h[k*4+1]);
                    hr[k*4+2] = fmaf(alpha, w[2], h[k*4+2]);
                    hr[k*4+3] = fmaf(alpha, w[3], h[k*4+3]);
                    p0 = fmaf(hr[k*4+0], hr[k*4+0], p0);
                    p1 = fmaf(hr[k*4+1], hr[k*4+1], p1);
                    p2 = fmaf(hr[k*4+2], hr[k*4+2], p2);
                    p3 = fmaf(hr[k*4+3], hr[k*4+3], p3);
                }
                const float total = wave_red_sum((p0 + p1) + (p2 + p3));
                const float rt = __builtin_amdgcn_rsqf(fmaf(total, INVD, EPSV));
                r_keep = (lane == (m & 63)) ? rt : r_keep;
                #pragma unroll
                for (int e = 0; e < 16; ++e) h[e] = rt * hr[e];
            }

            // ---- r-flush every 64 steps (before refill: stores stay older
            // than the new loads so the next group's vmcnt(16) is exact) ----
            if (g == 1 && (tt & 63) == 56)
                rtab[(size_t)b * TT + (tt - 56) + lane] = r_keep;

            // ---- refill slots g*4..g*4+3 with rows m0+8..m0+11 ----
            #pragma unroll
            for (int s4 = 0; s4 < 4; ++s4) {
                const int s = g * 4 + s4;
                const float* wp = wbase + (size_t)((m0 + 8 + s4) & (TT - 1)) * BD;
                #pragma unroll
                for (int k = 0; k < 4; ++k)
                    asm volatile("global_load_dwordx4 %0, %1, off"
                                 : "=v"(buf[s][k]) : "v"(wp + k * 256));
            }
        }
    }

    asm volatile("s_waitcnt vmcnt(0)" ::: "memory");
}

// ---------------------------------------------------------------------------
// K3: phase B — parallel replay, single pass (r3-verbatim, proven).
// ---------------------------------------------------------------------------
__global__ __launch_bounds__(256)
void k_phaseB(float* __restrict__ WxOut, float* __restrict__ hout,
              const float* __restrict__ rtab, const float* __restrict__ la) {
    const int col = blockIdx.x * 256 + threadIdx.x;
    const int c = blockIdx.y;
    const int b = col >> 10;
    const float alpha = expf(la[0]);
    const float* rr = rtab + b * TT;
    float h = hout[(size_t)(c * CH) * BD + col];
    const int t0 = c * CH + 1;
    float w = WxOut[(size_t)(t0 - 1) * BD + col];
    for (int s = 0; s < CH; ++s) {
        const int t = t0 + s;
        float wnext = 0.f;
        if (s + 1 < CH) wnext = WxOut[(size_t)t * BD + col];
        const float r = rr[t - 1];
        const float hraw = fmaf(alpha, w, h);
        const float hn = r * hraw;
        const float sg = 1.0f / (1.0f + __expf(-hn));
        WxOut[(size_t)(t - 1) * BD + col] = hn * hn * sg;
        if ((t & (CH - 1)) != 0 || t == TT)
            hout[(size_t)t * BD + col] = hn;
        h = hn;
        w = wnext;
    }
}

// ---------------------------------------------------------------------------
extern "C" void kernel_launch(void* const* d_in, const int* in_sizes, int n_in,
                              void* d_out, int out_size, void* d_ws, size_t ws_size,
                              hipStream_t stream) {
    (void)in_sizes; (void)n_in; (void)out_size; (void)ws_size;
    const float* x    = (const float*)d_in[0];
    const float* h0   = (const float*)d_in[1];
    const float* W    = (const float*)d_in[2];
    const float* bias = (const float*)d_in[3];
    const float* la   = (const float*)d_in[4];

    float* outr = (float*)d_out;                       // [T][B*D] : Wx, then out
    float* hreg = outr + (size_t)TT * BD;              // [T+1][B*D] : h output
    unsigned short* xb = (unsigned short*)hreg;        // bf16 x (dead space pre-phase-A)
    unsigned short* wb = xb + (size_t)MR * DD;         // bf16 W
    float* rtab = (float*)d_ws;                        // [B][T] = 128KB (proven size)

    k_convert<<<2048, 256, 0, stream>>>(x, W, xb, wb);
    k_gemm<<<dim3(DD / 128, MR / 128), 256, 0, stream>>>(xb, wb, bias, outr);
    k_phaseA<<<BB, 64, 0, stream>>>(outr, h0, la, hreg, rtab);
    k_phaseB<<<dim3(BD / 256, NCH), 256, 0, stream>>>(outr, hreg, rtab, la);
}